// Round 16
// baseline (206.974 us; speedup 1.0000x reference)
//
#include <hip/hip_runtime.h>

typedef unsigned short u16;
typedef __attribute__((ext_vector_type(8))) __bf16 bf16x8;
typedef __attribute__((ext_vector_type(4))) float f32x4;
typedef __attribute__((ext_vector_type(16))) float f32x16;
typedef __attribute__((ext_vector_type(4))) unsigned short u16x4;
typedef __attribute__((ext_vector_type(8))) unsigned short u16x8;
typedef __attribute__((ext_vector_type(4))) unsigned int u32x4;

#define T_LEN 2048
#define B_SZ 4
#define E_DIM 1024
#define H_N 16
#define D_H 64
#define M_ROWS (T_LEN * B_SZ)   // 8192
#define NQT (T_LEN / 128)       // 16 q-tiles of 128 rows

__device__ __forceinline__ u16 f2bf(float f){
  unsigned u = __builtin_bit_cast(unsigned, f);
  u += 0x7fffu + ((u >> 16) & 1u);
  return (u16)(u >> 16);
}

__device__ __forceinline__ float fexp2(float x){
#if __has_builtin(__builtin_amdgcn_exp2f)
  return __builtin_amdgcn_exp2f(x);
#else
  return exp2f(x);
#endif
}

__device__ __forceinline__ unsigned cvtpk(float lo, float hi){
  unsigned w;
  asm("v_cvt_pk_bf16_f32 %0, %1, %2" : "=v"(w) : "v"(lo), "v"(hi));
  return w;
}
__device__ __forceinline__ float xhalf_max(float x){
  return fmaxf(x, __shfl_xor(x, 32));
}
__device__ __forceinline__ float xhalf_sum(float x){
  return x + __shfl_xor(x, 32);
}
// tree max over 16 lane-local values; fmaxf(fmaxf(m,a),b) fuses to v_max3_f32
__device__ __forceinline__ float vmax16(const f32x16 &v){
  float m = fmaxf(v[0], v[1]);
  m = fmaxf(fmaxf(m, v[2]),  v[3]);
  m = fmaxf(fmaxf(m, v[4]),  v[5]);
  m = fmaxf(fmaxf(m, v[6]),  v[7]);
  m = fmaxf(fmaxf(m, v[8]),  v[9]);
  m = fmaxf(fmaxf(m, v[10]), v[11]);
  m = fmaxf(fmaxf(m, v[12]), v[13]);
  m = fmaxf(fmaxf(m, v[14]), v[15]);
  return m;
}

__device__ __forceinline__ void load_lds16(const void* g, void* l){
  __builtin_amdgcn_global_load_lds(
      (const __attribute__((address_space(1))) void*)g,
      (__attribute__((address_space(3))) void*)l, 16, 0, 0);
}

// ---------------- fp32 -> bf16 convert, all 7 tensors in one launch ----------------
__global__ void cvt_all(
    const float* __restrict__ i0, const float* __restrict__ i1, const float* __restrict__ i2,
    const float* __restrict__ i3, const float* __restrict__ i4, const float* __restrict__ i5,
    const float* __restrict__ i6,
    u16* __restrict__ o0, u16* __restrict__ o1, u16* __restrict__ o2,
    u16* __restrict__ o3, u16* __restrict__ o4, u16* __restrict__ o5,
    u16* __restrict__ o6, int nX, int nW)
{
  const int z = blockIdx.z;
  const float* in; u16* out; int n;
  switch (z){
    case 0: in=i0; out=o0; n=nX; break;
    case 1: in=i1; out=o1; n=nX; break;
    case 2: in=i2; out=o2; n=nX; break;
    case 3: in=i3; out=o3; n=nW; break;
    case 4: in=i4; out=o4; n=nW; break;
    case 5: in=i5; out=o5; n=nW; break;
    default: in=i6; out=o6; n=nW; break;
  }
  int idx = (blockIdx.x * blockDim.x + threadIdx.x) * 4;
  int stride = gridDim.x * blockDim.x * 4;
  for (int i = idx; i < n; i += stride){
    float4 v = *(const float4*)(in + i);
    u16x4 o = { f2bf(v.x), f2bf(v.y), f2bf(v.z), f2bf(v.w) };
    *(u16x4*)(out + i) = o;
  }
}

// ======== GEMM core: 128x128 tile, BK=32, 256 thr / 4 waves (2x2), 4-buf LDS ========
// Depth-2 prefetch, counted vmcnt(4), ONE barrier per K-tile, 2 blocks/CU (64KB LDS).
#define G4_LDSU16 32768   // 64KB total: A 4x8KB @0, B 4x8KB @32768B

__device__ __forceinline__ void stageG(const u16* __restrict__ G, int r0g, int k0,
                                       char* base, int buf, int tid){
  #pragma unroll
  for (int r=0;r<2;++r){
    int c = r*256 + tid;
    int row = c >> 2;
    int colb = ((c & 3) * 16) ^ (((row >> 2) & 3) << 4);
    load_lds16((const char*)(G + (size_t)(r0g + row)*E_DIM + k0) + colb,
               base + buf*8192 + (size_t)(r*256 + (tid >> 6)*64)*16);
  }
}

__device__ __forceinline__ void gemm4_mainloop(
    const u16* __restrict__ A, const u16* __restrict__ Bt,
    int m0, int n0, u16* smem, f32x4 (&acc)[4][4])
{
  constexpr int NT = E_DIM / 32;     // 32 K-tiles
  const int tid = threadIdx.x;
  const int lane = tid & 63;
  const int w = tid >> 6;
  const int wr = w >> 1, wc = w & 1;
  const int lr = lane & 15, lg = lane >> 4;
  char* Abase = (char*)smem;
  char* Bbase = (char*)smem + 32768;

  #pragma unroll
  for (int i=0;i<4;i++)
    #pragma unroll
    for (int j=0;j<4;j++) acc[i][j] = (f32x4){0.f,0.f,0.f,0.f};

  stageG(A,  m0, 0,  Abase, 0, tid);
  stageG(Bt, n0, 0,  Bbase, 0, tid);
  stageG(A,  m0, 32, Abase, 1, tid);
  stageG(Bt, n0, 32, Bbase, 1, tid);
  asm volatile("s_waitcnt vmcnt(4)\n" ::: "memory");   // tile 0 resident
  __builtin_amdgcn_sched_barrier(0);
  __builtin_amdgcn_s_barrier();

  const int cbx = (lg*16) ^ (((lr >> 2) & 3) << 4);

  for (int t = 0; t < NT; ++t){
    const int buf = t & 3;
    if (t + 2 < NT){
      stageG(A,  m0, (t+2)*32, Abase, (t+2) & 3, tid);
      stageG(Bt, n0, (t+2)*32, Bbase, (t+2) & 3, tid);
    }
    char* Ac = Abase + buf*8192;
    char* Bc = Bbase + buf*8192;
    bf16x8 af[4], bfr[4];
    #pragma unroll
    for (int i=0;i<4;i++){
      af[i]  = *(const bf16x8*)(Ac + (wr*64 + i*16 + lr)*64 + cbx);
      bfr[i] = *(const bf16x8*)(Bc + (wc*64 + i*16 + lr)*64 + cbx);
    }
    asm volatile("s_waitcnt lgkmcnt(0)\n" ::: "memory");
    __builtin_amdgcn_sched_barrier(0);
    __builtin_amdgcn_s_setprio(1);
    #pragma unroll
    for (int i=0;i<4;i++)
      #pragma unroll
      for (int j=0;j<4;j++)
        acc[i][j] = __builtin_amdgcn_mfma_f32_16x16x32_bf16(af[i], bfr[j], acc[i][j], 0,0,0);
    __builtin_amdgcn_s_setprio(0);
    if (t + 2 < NT)      asm volatile("s_waitcnt vmcnt(4)\n" ::: "memory");
    else if (t + 1 < NT) asm volatile("s_waitcnt vmcnt(0)\n" ::: "memory");
    __builtin_amdgcn_sched_barrier(0);
    __builtin_amdgcn_s_barrier();
  }
}

// XCD remap: 512 blocks/GEMM, XCD c owns m-panels [8c,8c+8) x all 8 n-tiles
__device__ __forceinline__ void xcd_remap_gemm(int &m0, int &n0){
  int L = blockIdx.y * 8 + blockIdx.x;     // [0,512)
  int c = L & 7, i = L >> 3;               // i in [0,64)
  int by = c*8 + (i & 7);                  // [0,64)
  int bx = i >> 3;                         // [0,8)
  m0 = by * 128; n0 = bx * 128;
}

struct QKVArgs {
  const u16* A[3]; const u16* Bw[3]; const float* bias[3];
  float scale[3]; u16* out[3];
};

// Q/K/V projections. Writes bf16 [B,H,L,D].
__global__ __launch_bounds__(256) void gemm_qkv(QKVArgs args){
  __shared__ __align__(16) u16 smem[G4_LDSU16];
  const int z = blockIdx.z;
  int m0, n0; xcd_remap_gemm(m0, n0);
  f32x4 acc[4][4];
  gemm4_mainloop(args.A[z], args.Bw[z], m0, n0, smem, acc);

  const int lane = threadIdx.x & 63;
  const int w = threadIdx.x >> 6;
  const int wr = w >> 1, wc = w & 1;
  const int lr = lane & 15, lg = lane >> 4;
  const float* bias = args.bias[z];
  const float scale = args.scale[z];
  u16* outB = args.out[z];
  #pragma unroll
  for (int i=0;i<4;i++)
    #pragma unroll
    for (int j=0;j<4;j++)
      #pragma unroll
      for (int q=0;q<4;q++){
        int m = m0 + wr*64 + i*16 + lg*4 + q;
        int n = n0 + wc*64 + j*16 + lr;
        float v = (acc[i][j][q] + bias[n]) * scale;
        int t = m >> 2, b = m & 3;             // rows of [L,B,E]: m = t*B + b
        int h = n >> 6, d = n & 63;
        outB[ ((size_t)(b*H_N + h)*T_LEN + t)*D_H + d ] = f2bf(v);
      }
}

// Output projection: AO [B,T,E] -> d_out [T,B,E] fp32
__global__ __launch_bounds__(256) void gemm_out(
    const u16* __restrict__ A, const u16* __restrict__ Bt,
    const float* __restrict__ bias, float* __restrict__ outF)
{
  __shared__ __align__(16) u16 smem[G4_LDSU16];
  int m0, n0; xcd_remap_gemm(m0, n0);
  f32x4 acc[4][4];
  gemm4_mainloop(A, Bt, m0, n0, smem, acc);

  const int lane = threadIdx.x & 63;
  const int w = threadIdx.x >> 6;
  const int wr = w >> 1, wc = w & 1;
  const int lr = lane & 15, lg = lane >> 4;
  #pragma unroll
  for (int i=0;i<4;i++)
    #pragma unroll
    for (int j=0;j<4;j++)
      #pragma unroll
      for (int q=0;q<4;q++){
        int m = m0 + wr*64 + i*16 + lg*4 + q;
        int n = n0 + wc*64 + j*16 + lr;
        float v = acc[i][j][q] + bias[n];
        int b = m >> 11, t = m & 2047;         // rows of AO [B,T,E]: m = b*T + t
        outF[ (size_t)(t*B_SZ + b)*E_DIM + n ] = v;
      }
}

// ---------------- V transpose: [B,H,S,D] -> [B,H,D,S], s quad-permuted ----------------
__global__ __launch_bounds__(256) void transpose_v(const u16* __restrict__ Vb, u16* __restrict__ Vt){
  __shared__ u16 tile[64][65];
  int bh = blockIdx.y, s0 = blockIdx.x * 64;
  const u16* src = Vb + ((size_t)bh*T_LEN + s0)*D_H;
  u16* dst = Vt + (size_t)bh*D_H*T_LEN + s0;
  int tid = threadIdx.x;
  #pragma unroll
  for (int r=0;r<2;++r){
    int c = r*256 + tid;
    int s = c >> 3, d0 = (c & 7)*8;
    u16x8 v = *(const u16x8*)(src + (size_t)s*D_H + d0);
    #pragma unroll
    for (int j=0;j<8;j++) tile[d0+j][s] = v[j];
  }
  __syncthreads();
  #pragma unroll
  for (int r=0;r<2;++r){
    int c = r*256 + tid;
    int d = c >> 3, s1 = (c & 7)*8;
    u16x8 v;
    #pragma unroll
    for (int j=0;j<8;j++){
      int p = s1 + j;
      int sp = (p & ~12) | ((p & 4) << 1) | ((p & 8) >> 1);   // involution
      v[j] = tile[d][sp];
    }
    *(u16x8*)(dst + (size_t)d*T_LEN + s1) = v;
  }
}

// ---------------- causal flash attention, 32x32 MFMA, QBLK=128, KVBLK=64 ----------------
// R15 structure + depth-2 counted-vmcnt pipeline (T4): 4 K/V buffers, stage j+2
// while computing j, ONE s_waitcnt vmcnt(4) per tile, raw s_barrier (no vmcnt-0 drain).
__global__ __launch_bounds__(256) void attn_fwd(
    const u16* __restrict__ Qb, const u16* __restrict__ Kb,
    const u16* __restrict__ Vt, u16* __restrict__ AO)
{
  __shared__ __align__(16) u16 smem[8*64*64];   // 64KB: Ks 4x8KB @0, Vs 4x8KB @32KB
  u16* Ks = smem;
  u16* Vs = smem + 4*64*64;
  const int tid = threadIdx.x;
  const int lane = tid & 63;
  const int wq = tid >> 6;
  const int l31 = lane & 31;
  const int hi = lane >> 5;
  int bh, px;
  {
    int L = blockIdx.y * 8 + blockIdx.x;
    int c = L & 7, i2 = L >> 3;
    bh = c*8 + (i2 & 7);
    px = i2 >> 3;
  }
  const u16* Kbase = Kb + (size_t)bh * T_LEN * D_H;
  const u16* Vbase = Vt + (size_t)bh * D_H * T_LEN;
  const int b_ = bh >> 4, h = bh & 15;

  auto STAGE = [&](int j, int b){
    int s0 = j * 64;
    #pragma unroll
    for (int r=0;r<2;++r){
      int c = r*256 + tid;
      int row = c >> 3;
      int colb = (c & 7) * 16;
      int scolb = colb ^ ((row & 7) << 4);
      load_lds16((const char*)(Kbase + (size_t)(s0 + row)*D_H) + scolb,
                 (char*)Ks + b*8192 + (r*256 + wq*64)*16);
      load_lds16((const char*)(Vbase + (size_t)row*T_LEN + s0) + scolb,
                 (char*)Vs + b*8192 + (r*256 + wq*64)*16);
    }
  };

  #pragma unroll 1
  for (int ph = 0; ph < 2; ++ph){
    const int qt = ph ? px : (NQT - 1 - px);
    const int qb = qt * 128;
    const int qg = qb + wq*32 + l31;

    bf16x8 qf[4];
    {
      const u16* qp = Qb + (size_t)bh*T_LEN*D_H + (size_t)qg*D_H + hi*8;
      #pragma unroll
      for (int kk=0;kk<4;++kk) qf[kk] = *(const bf16x8*)(qp + kk*16);
    }

    f32x16 o[2];
    #pragma unroll
    for (int f=0;f<2;++f)
      #pragma unroll
      for (int r=0;r<16;++r) o[f][r] = 0.f;
    float m_run = -INFINITY, l_run = 0.f;

    const int ntiles = 2*qt + 2;           // always >= 2
    __syncthreads();                        // prior phase's smem reads complete
    STAGE(0, 0);
    STAGE(1, 1);
    asm volatile("s_waitcnt vmcnt(4)\n" ::: "memory");   // tile 0 resident
    __builtin_amdgcn_sched_barrier(0);
    __builtin_amdgcn_s_barrier();

    for (int j = 0; j < ntiles; ++j){
      const int cur = j & 3;
      if (j + 2 < ntiles) STAGE(j+2, (j+2) & 3);
      const char* Kc = (const char*)Ks + cur*8192;
      const char* Vc = (const char*)Vs + cur*8192;

      const bool fullmask = (j == 2*qt + 1) && (wq < 2);
      if (!fullmask){
        f32x16 st[2];
        #pragma unroll
        for (int i=0;i<2;++i)
          #pragma unroll
          for (int r=0;r<16;++r) st[i][r] = 0.f;
        __builtin_amdgcn_s_setprio(1);
        #pragma unroll
        for (int i=0;i<2;++i){
          #pragma unroll
          for (int kk=0;kk<4;++kk){
            int row = i*32 + l31;
            int colb = (kk*32 + hi*16) ^ ((row & 7) << 4);
            bf16x8 kf = *(const bf16x8*)(Kc + row*128 + colb);
            st[i] = __builtin_amdgcn_mfma_f32_32x32x16_bf16(kf, qf[kk], st[i], 0,0,0);
          }
        }
        __builtin_amdgcn_s_setprio(0);

        const int s0 = j*64;
        float mx = -INFINITY;
        if (j >= 2*qt){
          #pragma unroll
          for (int i=0;i<2;++i)
            #pragma unroll
            for (int r=0;r<16;++r){
              int sg = s0 + i*32 + (r&3) + 8*(r>>2) + 4*hi;
              float v = (sg > qg) ? -INFINITY : st[i][r];
              st[i][r] = v;
              mx = fmaxf(mx, v);
            }
        } else {
          mx = fmaxf(vmax16(st[0]), vmax16(st[1]));
        }
        mx = xhalf_max(mx);

        // defer-max: rescale only when needed (P bounded by 2^8)
        if (!__all(mx <= m_run + 8.0f)){
          float m_new = fmaxf(m_run, mx);
          float sc = fexp2(m_run - m_new);
          l_run *= sc;
          #pragma unroll
          for (int f=0;f<2;++f)
            #pragma unroll
            for (int r=0;r<16;++r) o[f][r] *= sc;
          m_run = m_new;
        }

        // exp + tree row-sum (4 independent chains)
        float rs0 = 0.f, rs1 = 0.f, rs2 = 0.f, rs3 = 0.f;
        #pragma unroll
        for (int i=0;i<2;++i)
          #pragma unroll
          for (int r=0;r<16;++r){
            float p = fexp2(st[i][r] - m_run);
            st[i][r] = p;
            if ((r & 3) == 0) rs0 += p;
            else if ((r & 3) == 1) rs1 += p;
            else if ((r & 3) == 2) rs2 += p;
            else rs3 += p;
          }
        float rsum = (rs0 + rs1) + (rs2 + rs3);
        rsum = xhalf_sum(rsum);
        l_run += rsum;

        // pack P into PV B-fragments (V s-order quad-permuted to match)
        u32x4 Bfr[4];
        #pragma unroll
        for (int i=0;i<2;++i){
          Bfr[2*i]   = (u32x4){ cvtpk(st[i][0],  st[i][1]),  cvtpk(st[i][2],  st[i][3]),
                                cvtpk(st[i][4],  st[i][5]),  cvtpk(st[i][6],  st[i][7]) };
          Bfr[2*i+1] = (u32x4){ cvtpk(st[i][8],  st[i][9]),  cvtpk(st[i][10], st[i][11]),
                                cvtpk(st[i][12], st[i][13]), cvtpk(st[i][14], st[i][15]) };
        }

        // O^T += V^T · P^T
        __builtin_amdgcn_s_setprio(1);
        #pragma unroll
        for (int ss=0; ss<4; ++ss){
          bf16x8 pb = __builtin_bit_cast(bf16x8, Bfr[ss]);
          #pragma unroll
          for (int f=0; f<2; ++f){
            int row = f*32 + l31;
            int colb = (ss*32 + hi*16) ^ ((row & 7) << 4);
            bf16x8 vf = *(const bf16x8*)(Vc + row*128 + colb);
            o[f] = __builtin_amdgcn_mfma_f32_32x32x16_bf16(vf, pb, o[f], 0,0,0);
          }
        }
        __builtin_amdgcn_s_setprio(0);
      }
      // counted drain: keep j+2's 4 loads in flight; retire j+1's
      if (j + 2 < ntiles)      asm volatile("s_waitcnt vmcnt(4)\n" ::: "memory");
      else if (j + 1 < ntiles) asm volatile("s_waitcnt vmcnt(0)\n" ::: "memory");
      __builtin_amdgcn_sched_barrier(0);
      __builtin_amdgcn_s_barrier();
    }

    float linv = 1.f / l_run;
    {
      char* Osh = (char*)smem;
      unsigned base = wq*4352;
      #pragma unroll
      for (int f=0;f<2;++f)
        #pragma unroll
        for (int m=0;m<8;++m){
          unsigned word = cvtpk(o[f][2*m]*linv, o[f][2*m+1]*linv);
          int d0 = (m&1)*2 + 8*(m>>1) + 4*hi + 32*f;
          *(unsigned*)(Osh + base + l31*136 + d0*2) = word;
        }
    }
    __syncthreads();
    {
      int q = tid >> 1, half = tid & 1;
      const char* src = (const char*)smem + (q>>5)*4352 + (q&31)*136 + half*64;
      u16* dst = AO + ((size_t)(b_*T_LEN + qb + q))*E_DIM + h*D_H + half*32;
      #pragma unroll
      for (int k=0;k<4;++k)
        *(u16x8*)(dst + k*8) = *(const u16x8*)(src + k*16);
    }
  }
}

extern "C" void kernel_launch(void* const* d_in, const int* in_sizes, int n_in,
                              void* d_out, int out_size, void* d_ws, size_t ws_size,
                              hipStream_t stream){
  const float* query = (const float*)d_in[0];
  const float* key   = (const float*)d_in[1];
  const float* value = (const float*)d_in[2];
  const float* Wq = (const float*)d_in[4];
  const float* bq = (const float*)d_in[5];
  const float* Wk = (const float*)d_in[6];
  const float* bk = (const float*)d_in[7];
  const float* Wv = (const float*)d_in[8];
  const float* bv = (const float*)d_in[9];
  const float* Wo = (const float*)d_in[10];
  const float* bo = (const float*)d_in[11];

  char* ws = (char*)d_ws;
  const size_t SZ_X = (size_t)M_ROWS * E_DIM * 2;   // 16 MB
  const size_t SZ_W = (size_t)E_DIM * E_DIM * 2;    // 2 MB
  u16* Xq  = (u16*)(ws);                    // reused as AO after Q-proj
  u16* Xk  = (u16*)(ws + SZ_X);             // reused as Vt after K-proj
  u16* Xv  = (u16*)(ws + 2*SZ_X);
  u16* Wqb = (u16*)(ws + 3*SZ_X);
  u16* Wkb = (u16*)(ws + 3*SZ_X + 1*SZ_W);
  u16* Wvb = (u16*)(ws + 3*SZ_X + 2*SZ_W);
  u16* Wob = (u16*)(ws + 3*SZ_X + 3*SZ_W);
  u16* Qb  = (u16*)(ws + 3*SZ_X + 4*SZ_W);
  u16* Kb  = (u16*)(ws + 4*SZ_X + 4*SZ_W);
  u16* Vb  = (u16*)(ws + 5*SZ_X + 4*SZ_W);
  u16* Vt  = Xk;
  u16* AO  = Xq;

  const int nX = M_ROWS * E_DIM;
  const int nW = E_DIM * E_DIM;
  cvt_all<<<dim3(1024,1,7), 256, 0, stream>>>(
      query, key, value, Wq, Wk, Wv, Wo,
      Xq, Xk, Xv, Wqb, Wkb, Wvb, Wob, nX, nW);

  const float QSCALE = 0.125f * 1.44269504f;   // 1/sqrt(D) * log2(e)
  QKVArgs qa;
  qa.A[0]=Xq;  qa.A[1]=Xk;  qa.A[2]=Xv;
  qa.Bw[0]=Wqb; qa.Bw[1]=Wkb; qa.Bw[2]=Wvb;
  qa.bias[0]=bq; qa.bias[1]=bk; qa.bias[2]=bv;
  qa.scale[0]=QSCALE; qa.scale[1]=1.0f; qa.scale[2]=1.0f;
  qa.out[0]=Qb; qa.out[1]=Kb; qa.out[2]=Vb;
  gemm_qkv<<<dim3(8, M_ROWS/128, 3), 256, 0, stream>>>(qa);
  transpose_v<<<dim3(T_LEN/64, B_SZ*H_N), 256, 0, stream>>>(Vb, Vt);
  attn_fwd<<<dim3(8, B_SZ*H_N), 256, 0, stream>>>(Qb, Kb, Vt, AO);
  gemm_out<<<dim3(8, M_ROWS/128), 256, 0, stream>>>(AO, Wob, bo, (float*)d_out);
}

// Round 17
// 178.574 us; speedup vs baseline: 1.1590x; 1.1590x over previous
//
#include <hip/hip_runtime.h>

typedef unsigned short u16;
typedef __attribute__((ext_vector_type(8))) __bf16 bf16x8;
typedef __attribute__((ext_vector_type(4))) float f32x4;
typedef __attribute__((ext_vector_type(16))) float f32x16;
typedef __attribute__((ext_vector_type(4))) unsigned short u16x4;
typedef __attribute__((ext_vector_type(8))) unsigned short u16x8;
typedef __attribute__((ext_vector_type(4))) unsigned int u32x4;

#define T_LEN 2048
#define B_SZ 4
#define E_DIM 1024
#define H_N 16
#define D_H 64
#define M_ROWS (T_LEN * B_SZ)   // 8192
#define NQT (T_LEN / 128)       // 16 q-tiles of 128 rows

__device__ __forceinline__ u16 f2bf(float f){
  unsigned u = __builtin_bit_cast(unsigned, f);
  u += 0x7fffu + ((u >> 16) & 1u);
  return (u16)(u >> 16);
}

__device__ __forceinline__ float fexp2(float x){
#if __has_builtin(__builtin_amdgcn_exp2f)
  return __builtin_amdgcn_exp2f(x);
#else
  return exp2f(x);
#endif
}

__device__ __forceinline__ unsigned cvtpk(float lo, float hi){
  unsigned w;
  asm("v_cvt_pk_bf16_f32 %0, %1, %2" : "=v"(w) : "v"(lo), "v"(hi));
  return w;
}
__device__ __forceinline__ float xhalf_max(float x){
  return fmaxf(x, __shfl_xor(x, 32));
}
__device__ __forceinline__ float xhalf_sum(float x){
  return x + __shfl_xor(x, 32);
}
// tree max over 16 lane-local values; fmaxf(fmaxf(m,a),b) fuses to v_max3_f32
__device__ __forceinline__ float vmax16(const f32x16 &v){
  float m = fmaxf(v[0], v[1]);
  m = fmaxf(fmaxf(m, v[2]),  v[3]);
  m = fmaxf(fmaxf(m, v[4]),  v[5]);
  m = fmaxf(fmaxf(m, v[6]),  v[7]);
  m = fmaxf(fmaxf(m, v[8]),  v[9]);
  m = fmaxf(fmaxf(m, v[10]), v[11]);
  m = fmaxf(fmaxf(m, v[12]), v[13]);
  m = fmaxf(fmaxf(m, v[14]), v[15]);
  return m;
}

__device__ __forceinline__ void load_lds16(const void* g, void* l){
  __builtin_amdgcn_global_load_lds(
      (const __attribute__((address_space(1))) void*)g,
      (__attribute__((address_space(3))) void*)l, 16, 0, 0);
}

// ---------------- fp32 -> bf16 convert, all 7 tensors in one launch ----------------
__global__ void cvt_all(
    const float* __restrict__ i0, const float* __restrict__ i1, const float* __restrict__ i2,
    const float* __restrict__ i3, const float* __restrict__ i4, const float* __restrict__ i5,
    const float* __restrict__ i6,
    u16* __restrict__ o0, u16* __restrict__ o1, u16* __restrict__ o2,
    u16* __restrict__ o3, u16* __restrict__ o4, u16* __restrict__ o5,
    u16* __restrict__ o6, int nX, int nW)
{
  const int z = blockIdx.z;
  const float* in; u16* out; int n;
  switch (z){
    case 0: in=i0; out=o0; n=nX; break;
    case 1: in=i1; out=o1; n=nX; break;
    case 2: in=i2; out=o2; n=nX; break;
    case 3: in=i3; out=o3; n=nW; break;
    case 4: in=i4; out=o4; n=nW; break;
    case 5: in=i5; out=o5; n=nW; break;
    default: in=i6; out=o6; n=nW; break;
  }
  int idx = (blockIdx.x * blockDim.x + threadIdx.x) * 4;
  int stride = gridDim.x * blockDim.x * 4;
  for (int i = idx; i < n; i += stride){
    float4 v = *(const float4*)(in + i);
    u16x4 o = { f2bf(v.x), f2bf(v.y), f2bf(v.z), f2bf(v.w) };
    *(u16x4*)(out + i) = o;
  }
}

// ======== GEMM core: 128x128 tile, BK=32, 256 thr / 4 waves (2x2), 4-buf LDS ========
// Depth-2 prefetch, counted vmcnt(4), ONE barrier per K-tile, 2 blocks/CU (64KB LDS).
#define G4_LDSU16 32768   // 64KB total: A 4x8KB @0, B 4x8KB @32768B

__device__ __forceinline__ void stageG(const u16* __restrict__ G, int r0g, int k0,
                                       char* base, int buf, int tid){
  #pragma unroll
  for (int r=0;r<2;++r){
    int c = r*256 + tid;
    int row = c >> 2;
    int colb = ((c & 3) * 16) ^ (((row >> 2) & 3) << 4);
    load_lds16((const char*)(G + (size_t)(r0g + row)*E_DIM + k0) + colb,
               base + buf*8192 + (size_t)(r*256 + (tid >> 6)*64)*16);
  }
}

__device__ __forceinline__ void gemm4_mainloop(
    const u16* __restrict__ A, const u16* __restrict__ Bt,
    int m0, int n0, u16* smem, f32x4 (&acc)[4][4])
{
  constexpr int NT = E_DIM / 32;     // 32 K-tiles
  const int tid = threadIdx.x;
  const int lane = tid & 63;
  const int w = tid >> 6;
  const int wr = w >> 1, wc = w & 1;
  const int lr = lane & 15, lg = lane >> 4;
  char* Abase = (char*)smem;
  char* Bbase = (char*)smem + 32768;

  #pragma unroll
  for (int i=0;i<4;i++)
    #pragma unroll
    for (int j=0;j<4;j++) acc[i][j] = (f32x4){0.f,0.f,0.f,0.f};

  stageG(A,  m0, 0,  Abase, 0, tid);
  stageG(Bt, n0, 0,  Bbase, 0, tid);
  stageG(A,  m0, 32, Abase, 1, tid);
  stageG(Bt, n0, 32, Bbase, 1, tid);
  asm volatile("s_waitcnt vmcnt(4)\n" ::: "memory");   // tile 0 resident
  __builtin_amdgcn_sched_barrier(0);
  __builtin_amdgcn_s_barrier();

  const int cbx = (lg*16) ^ (((lr >> 2) & 3) << 4);

  for (int t = 0; t < NT; ++t){
    const int buf = t & 3;
    if (t + 2 < NT){
      stageG(A,  m0, (t+2)*32, Abase, (t+2) & 3, tid);
      stageG(Bt, n0, (t+2)*32, Bbase, (t+2) & 3, tid);
    }
    char* Ac = Abase + buf*8192;
    char* Bc = Bbase + buf*8192;
    bf16x8 af[4], bfr[4];
    #pragma unroll
    for (int i=0;i<4;i++){
      af[i]  = *(const bf16x8*)(Ac + (wr*64 + i*16 + lr)*64 + cbx);
      bfr[i] = *(const bf16x8*)(Bc + (wc*64 + i*16 + lr)*64 + cbx);
    }
    asm volatile("s_waitcnt lgkmcnt(0)\n" ::: "memory");
    __builtin_amdgcn_sched_barrier(0);
    __builtin_amdgcn_s_setprio(1);
    #pragma unroll
    for (int i=0;i<4;i++)
      #pragma unroll
      for (int j=0;j<4;j++)
        acc[i][j] = __builtin_amdgcn_mfma_f32_16x16x32_bf16(af[i], bfr[j], acc[i][j], 0,0,0);
    __builtin_amdgcn_s_setprio(0);
    if (t + 2 < NT)      asm volatile("s_waitcnt vmcnt(4)\n" ::: "memory");
    else if (t + 1 < NT) asm volatile("s_waitcnt vmcnt(0)\n" ::: "memory");
    __builtin_amdgcn_sched_barrier(0);
    __builtin_amdgcn_s_barrier();
  }
}

// XCD remap: 512 blocks/GEMM, XCD c owns m-panels [8c,8c+8) x all 8 n-tiles
__device__ __forceinline__ void xcd_remap_gemm(int &m0, int &n0){
  int L = blockIdx.y * 8 + blockIdx.x;     // [0,512)
  int c = L & 7, i = L >> 3;               // i in [0,64)
  int by = c*8 + (i & 7);                  // [0,64)
  int bx = i >> 3;                         // [0,8)
  m0 = by * 128; n0 = bx * 128;
}

struct QKVArgs {
  const u16* A[3]; const u16* Bw[3]; const float* bias[3];
  float scale[3]; u16* out[3];
};

// Q/K/V projections. z=0/1 write bf16 [B,H,L,D]; z=2 writes Vt [B,H,D,S] directly
// (s quad-permuted: position p holds s=perm(p), matching attn's PV fragment layout).
__global__ __launch_bounds__(256) void gemm_qkv(QKVArgs args){
  __shared__ __align__(16) u16 smem[G4_LDSU16];
  const int z = blockIdx.z;
  int m0, n0; xcd_remap_gemm(m0, n0);
  f32x4 acc[4][4];
  gemm4_mainloop(args.A[z], args.Bw[z], m0, n0, smem, acc);

  const int tid = threadIdx.x;
  const int lane = tid & 63;
  const int w = tid >> 6;
  const int wr = w >> 1, wc = w & 1;
  const int lr = lane & 15, lg = lane >> 4;
  const float* bias = args.bias[z];
  u16* outB = args.out[z];

  if (z == 2){
    // ---- fused V transpose: C-tile -> LDS -> Vt[bh][d][t0..t0+32) ----
    u16* tile = smem;   // [128 n][132] u16 = 33KB (main loop done, LDS free)
    #pragma unroll
    for (int i=0;i<4;i++)
      #pragma unroll
      for (int j=0;j<4;j++){
        int n_local = wc*64 + j*16 + lr;
        u16x4 pk;
        #pragma unroll
        for (int q=0;q<4;q++) pk[q] = f2bf(acc[i][j][q] + bias[n0 + n_local]);
        *(u16x4*)&tile[n_local*132 + wr*64 + i*16 + lg*4] = pk;
      }
    __syncthreads();
    const int t0 = m0 >> 2;                 // 32 t-values per tile (m = t*4 + b)
    #pragma unroll
    for (int rr=0; rr<2; ++rr){
      int rho = (tid << 1) | rr;            // [0,512): (b, h_local, d)
      int vb = rho >> 7;
      int vh = (rho >> 6) & 1;
      int vd = rho & 63;
      int n_local = vh*64 + vd;
      int bh2 = vb*H_N + (n0 >> 6) + vh;
      u16* dst = outB + ((size_t)bh2*D_H + vd)*T_LEN + t0;
      #pragma unroll
      for (int g=0; g<4; ++g){
        u16x8 vv;
        #pragma unroll
        for (int e=0; e<8; ++e){
          int p = g*8 + e;
          int sp = (p & ~12) | ((p & 4) << 1) | ((p & 8) >> 1);   // quad-perm involution
          vv[e] = tile[n_local*132 + sp*4 + vb];
        }
        *(u16x8*)(dst + g*8) = vv;
      }
    }
  } else {
    const float scale = args.scale[z];
    #pragma unroll
    for (int i=0;i<4;i++)
      #pragma unroll
      for (int j=0;j<4;j++)
        #pragma unroll
        for (int q=0;q<4;q++){
          int m = m0 + wr*64 + i*16 + lg*4 + q;
          int n = n0 + wc*64 + j*16 + lr;
          float v = (acc[i][j][q] + bias[n]) * scale;
          int t = m >> 2, b = m & 3;             // rows of [L,B,E]: m = t*B + b
          int h = n >> 6, d = n & 63;
          outB[ ((size_t)(b*H_N + h)*T_LEN + t)*D_H + d ] = f2bf(v);
        }
  }
}

// Output projection: AO [B,T,E] -> d_out [T,B,E] fp32
__global__ __launch_bounds__(256) void gemm_out(
    const u16* __restrict__ A, const u16* __restrict__ Bt,
    const float* __restrict__ bias, float* __restrict__ outF)
{
  __shared__ __align__(16) u16 smem[G4_LDSU16];
  int m0, n0; xcd_remap_gemm(m0, n0);
  f32x4 acc[4][4];
  gemm4_mainloop(A, Bt, m0, n0, smem, acc);

  const int lane = threadIdx.x & 63;
  const int w = threadIdx.x >> 6;
  const int wr = w >> 1, wc = w & 1;
  const int lr = lane & 15, lg = lane >> 4;
  #pragma unroll
  for (int i=0;i<4;i++)
    #pragma unroll
    for (int j=0;j<4;j++)
      #pragma unroll
      for (int q=0;q<4;q++){
        int m = m0 + wr*64 + i*16 + lg*4 + q;
        int n = n0 + wc*64 + j*16 + lr;
        float v = acc[i][j][q] + bias[n];
        int b = m >> 11, t = m & 2047;         // rows of AO [B,T,E]: m = b*T + t
        outF[ (size_t)(t*B_SZ + b)*E_DIM + n ] = v;
      }
}

// ---------------- causal flash attention, 32x32 MFMA, QBLK=128, KVBLK=64 ----------------
// R15 structure (proven 74.4us): 2-phase, 2-buffer, tree max/rsum, in-register P.
__global__ __launch_bounds__(256) void attn_fwd(
    const u16* __restrict__ Qb, const u16* __restrict__ Kb,
    const u16* __restrict__ Vt, u16* __restrict__ AO)
{
  __shared__ __align__(16) u16 smem[4*64*64];
  u16* Ks = smem;
  u16* Vs = smem + 2*64*64;
  const int tid = threadIdx.x;
  const int lane = tid & 63;
  const int wq = tid >> 6;
  const int l31 = lane & 31;
  const int hi = lane >> 5;
  int bh, px;
  {
    int L = blockIdx.y * 8 + blockIdx.x;
    int c = L & 7, i2 = L >> 3;
    bh = c*8 + (i2 & 7);
    px = i2 >> 3;
  }
  const u16* Kbase = Kb + (size_t)bh * T_LEN * D_H;
  const u16* Vbase = Vt + (size_t)bh * D_H * T_LEN;
  const int b_ = bh >> 4, h = bh & 15;

  auto STAGE = [&](int j, int b){
    int s0 = j * 64;
    #pragma unroll
    for (int r=0;r<2;++r){
      int c = r*256 + tid;
      int row = c >> 3;
      int colb = (c & 7) * 16;
      int scolb = colb ^ ((row & 7) << 4);
      load_lds16((const char*)(Kbase + (size_t)(s0 + row)*D_H) + scolb,
                 (char*)Ks + b*8192 + (r*256 + wq*64)*16);
      load_lds16((const char*)(Vbase + (size_t)row*T_LEN + s0) + scolb,
                 (char*)Vs + b*8192 + (r*256 + wq*64)*16);
    }
  };

  #pragma unroll 1
  for (int ph = 0; ph < 2; ++ph){
    const int qt = ph ? px : (NQT - 1 - px);
    const int qb = qt * 128;
    const int qg = qb + wq*32 + l31;

    bf16x8 qf[4];
    {
      const u16* qp = Qb + (size_t)bh*T_LEN*D_H + (size_t)qg*D_H + hi*8;
      #pragma unroll
      for (int kk=0;kk<4;++kk) qf[kk] = *(const bf16x8*)(qp + kk*16);
    }

    f32x16 o[2];
    #pragma unroll
    for (int f=0;f<2;++f)
      #pragma unroll
      for (int r=0;r<16;++r) o[f][r] = 0.f;
    float m_run = -INFINITY, l_run = 0.f;

    const int ntiles = 2*qt + 2;
    __syncthreads();
    STAGE(0, 0);
    __syncthreads();

    for (int j = 0; j < ntiles; ++j){
      const int cur = j & 1;
      if (j + 1 < ntiles) STAGE(j+1, cur^1);
      const char* Kc = (const char*)Ks + cur*8192;
      const char* Vc = (const char*)Vs + cur*8192;

      const bool fullmask = (j == 2*qt + 1) && (wq < 2);
      if (!fullmask){
        f32x16 st[2];
        #pragma unroll
        for (int i=0;i<2;++i)
          #pragma unroll
          for (int r=0;r<16;++r) st[i][r] = 0.f;
        __builtin_amdgcn_s_setprio(1);
        #pragma unroll
        for (int i=0;i<2;++i){
          #pragma unroll
          for (int kk=0;kk<4;++kk){
            int row = i*32 + l31;
            int colb = (kk*32 + hi*16) ^ ((row & 7) << 4);
            bf16x8 kf = *(const bf16x8*)(Kc + row*128 + colb);
            st[i] = __builtin_amdgcn_mfma_f32_32x32x16_bf16(kf, qf[kk], st[i], 0,0,0);
          }
        }
        __builtin_amdgcn_s_setprio(0);

        const int s0 = j*64;
        float mx = -INFINITY;
        if (j >= 2*qt){
          #pragma unroll
          for (int i=0;i<2;++i)
            #pragma unroll
            for (int r=0;r<16;++r){
              int sg = s0 + i*32 + (r&3) + 8*(r>>2) + 4*hi;
              float v = (sg > qg) ? -INFINITY : st[i][r];
              st[i][r] = v;
              mx = fmaxf(mx, v);
            }
        } else {
          mx = fmaxf(vmax16(st[0]), vmax16(st[1]));
        }
        mx = xhalf_max(mx);

        // defer-max: rescale only when needed (P bounded by 2^8)
        if (!__all(mx <= m_run + 8.0f)){
          float m_new = fmaxf(m_run, mx);
          float sc = fexp2(m_run - m_new);
          l_run *= sc;
          #pragma unroll
          for (int f=0;f<2;++f)
            #pragma unroll
            for (int r=0;r<16;++r) o[f][r] *= sc;
          m_run = m_new;
        }

        // exp + tree row-sum (4 independent chains)
        float rs0 = 0.f, rs1 = 0.f, rs2 = 0.f, rs3 = 0.f;
        #pragma unroll
        for (int i=0;i<2;++i)
          #pragma unroll
          for (int r=0;r<16;++r){
            float p = fexp2(st[i][r] - m_run);
            st[i][r] = p;
            if ((r & 3) == 0) rs0 += p;
            else if ((r & 3) == 1) rs1 += p;
            else if ((r & 3) == 2) rs2 += p;
            else rs3 += p;
          }
        float rsum = (rs0 + rs1) + (rs2 + rs3);
        rsum = xhalf_sum(rsum);
        l_run += rsum;

        // pack P into PV B-fragments (V s-order quad-permuted to match)
        u32x4 Bfr[4];
        #pragma unroll
        for (int i=0;i<2;++i){
          Bfr[2*i]   = (u32x4){ cvtpk(st[i][0],  st[i][1]),  cvtpk(st[i][2],  st[i][3]),
                                cvtpk(st[i][4],  st[i][5]),  cvtpk(st[i][6],  st[i][7]) };
          Bfr[2*i+1] = (u32x4){ cvtpk(st[i][8],  st[i][9]),  cvtpk(st[i][10], st[i][11]),
                                cvtpk(st[i][12], st[i][13]), cvtpk(st[i][14], st[i][15]) };
        }

        // O^T += V^T · P^T
        __builtin_amdgcn_s_setprio(1);
        #pragma unroll
        for (int ss=0; ss<4; ++ss){
          bf16x8 pb = __builtin_bit_cast(bf16x8, Bfr[ss]);
          #pragma unroll
          for (int f=0; f<2; ++f){
            int row = f*32 + l31;
            int colb = (ss*32 + hi*16) ^ ((row & 7) << 4);
            bf16x8 vf = *(const bf16x8*)(Vc + row*128 + colb);
            o[f] = __builtin_amdgcn_mfma_f32_32x32x16_bf16(vf, pb, o[f], 0,0,0);
          }
        }
        __builtin_amdgcn_s_setprio(0);
      }
      __syncthreads();
    }

    float linv = 1.f / l_run;
    {
      char* Osh = (char*)smem;
      unsigned base = wq*4352;
      #pragma unroll
      for (int f=0;f<2;++f)
        #pragma unroll
        for (int m=0;m<8;++m){
          unsigned word = cvtpk(o[f][2*m]*linv, o[f][2*m+1]*linv);
          int d0 = (m&1)*2 + 8*(m>>1) + 4*hi + 32*f;
          *(unsigned*)(Osh + base + l31*136 + d0*2) = word;
        }
    }
    __syncthreads();
    {
      int q = tid >> 1, half = tid & 1;
      const char* src = (const char*)smem + (q>>5)*4352 + (q&31)*136 + half*64;
      u16* dst = AO + ((size_t)(b_*T_LEN + qb + q))*E_DIM + h*D_H + half*32;
      #pragma unroll
      for (int k=0;k<4;++k)
        *(u16x8*)(dst + k*8) = *(const u16x8*)(src + k*16);
    }
  }
}

extern "C" void kernel_launch(void* const* d_in, const int* in_sizes, int n_in,
                              void* d_out, int out_size, void* d_ws, size_t ws_size,
                              hipStream_t stream){
  const float* query = (const float*)d_in[0];
  const float* key   = (const float*)d_in[1];
  const float* value = (const float*)d_in[2];
  const float* Wq = (const float*)d_in[4];
  const float* bq = (const float*)d_in[5];
  const float* Wk = (const float*)d_in[6];
  const float* bk = (const float*)d_in[7];
  const float* Wv = (const float*)d_in[8];
  const float* bv = (const float*)d_in[9];
  const float* Wo = (const float*)d_in[10];
  const float* bo = (const float*)d_in[11];

  char* ws = (char*)d_ws;
  const size_t SZ_X = (size_t)M_ROWS * E_DIM * 2;   // 16 MB
  const size_t SZ_W = (size_t)E_DIM * E_DIM * 2;    // 2 MB
  u16* Xq  = (u16*)(ws);                    // reused as AO after Q-proj
  u16* Xk  = (u16*)(ws + SZ_X);
  u16* Xv  = (u16*)(ws + 2*SZ_X);
  u16* Wqb = (u16*)(ws + 3*SZ_X);
  u16* Wkb = (u16*)(ws + 3*SZ_X + 1*SZ_W);
  u16* Wvb = (u16*)(ws + 3*SZ_X + 2*SZ_W);
  u16* Wob = (u16*)(ws + 3*SZ_X + 3*SZ_W);
  u16* Qb  = (u16*)(ws + 3*SZ_X + 4*SZ_W);
  u16* Kb  = (u16*)(ws + 4*SZ_X + 4*SZ_W);
  u16* Vt  = (u16*)(ws + 5*SZ_X + 4*SZ_W);  // V written transposed directly by gemm_qkv z=2
  u16* AO  = Xq;

  const int nX = M_ROWS * E_DIM;
  const int nW = E_DIM * E_DIM;
  cvt_all<<<dim3(1024,1,7), 256, 0, stream>>>(
      query, key, value, Wq, Wk, Wv, Wo,
      Xq, Xk, Xv, Wqb, Wkb, Wvb, Wob, nX, nW);

  const float QSCALE = 0.125f * 1.44269504f;   // 1/sqrt(D) * log2(e)
  QKVArgs qa;
  qa.A[0]=Xq;  qa.A[1]=Xk;  qa.A[2]=Xv;
  qa.Bw[0]=Wqb; qa.Bw[1]=Wkb; qa.Bw[2]=Wvb;
  qa.bias[0]=bq; qa.bias[1]=bk; qa.bias[2]=bv;
  qa.scale[0]=QSCALE; qa.scale[1]=1.0f; qa.scale[2]=1.0f;
  qa.out[0]=Qb; qa.out[1]=Kb; qa.out[2]=Vt;
  gemm_qkv<<<dim3(8, M_ROWS/128, 3), 256, 0, stream>>>(qa);
  attn_fwd<<<dim3(8, B_SZ*H_N), 256, 0, stream>>>(Qb, Kb, Vt, AO);
  gemm_out<<<dim3(8, M_ROWS/128), 256, 0, stream>>>(AO, Wob, bo, (float*)d_out);
}

// Round 18
// 178.366 us; speedup vs baseline: 1.1604x; 1.0012x over previous
//
#include <hip/hip_runtime.h>

typedef unsigned short u16;
typedef __attribute__((ext_vector_type(8))) __bf16 bf16x8;
typedef __attribute__((ext_vector_type(4))) float f32x4;
typedef __attribute__((ext_vector_type(16))) float f32x16;
typedef __attribute__((ext_vector_type(4))) unsigned short u16x4;
typedef __attribute__((ext_vector_type(8))) unsigned short u16x8;
typedef __attribute__((ext_vector_type(4))) unsigned int u32x4;

#define T_LEN 2048
#define B_SZ 4
#define E_DIM 1024
#define H_N 16
#define D_H 64
#define M_ROWS (T_LEN * B_SZ)   // 8192
#define NQT (T_LEN / 128)       // 16 q-tiles of 128 rows

__device__ __forceinline__ u16 f2bf(float f){
  unsigned u = __builtin_bit_cast(unsigned, f);
  u += 0x7fffu + ((u >> 16) & 1u);
  return (u16)(u >> 16);
}

__device__ __forceinline__ float fexp2(float x){
#if __has_builtin(__builtin_amdgcn_exp2f)
  return __builtin_amdgcn_exp2f(x);
#else
  return exp2f(x);
#endif
}

__device__ __forceinline__ unsigned cvtpk(float lo, float hi){
  unsigned w;
  asm("v_cvt_pk_bf16_f32 %0, %1, %2" : "=v"(w) : "v"(lo), "v"(hi));
  return w;
}
__device__ __forceinline__ float xhalf_max(float x){
  return fmaxf(x, __shfl_xor(x, 32));
}
__device__ __forceinline__ float xhalf_sum(float x){
  return x + __shfl_xor(x, 32);
}
// tree max over 16 lane-local values; fmaxf(fmaxf(m,a),b) fuses to v_max3_f32
__device__ __forceinline__ float vmax16(const f32x16 &v){
  float m = fmaxf(v[0], v[1]);
  m = fmaxf(fmaxf(m, v[2]),  v[3]);
  m = fmaxf(fmaxf(m, v[4]),  v[5]);
  m = fmaxf(fmaxf(m, v[6]),  v[7]);
  m = fmaxf(fmaxf(m, v[8]),  v[9]);
  m = fmaxf(fmaxf(m, v[10]), v[11]);
  m = fmaxf(fmaxf(m, v[12]), v[13]);
  m = fmaxf(fmaxf(m, v[14]), v[15]);
  return m;
}

__device__ __forceinline__ void load_lds16(const void* g, void* l){
  __builtin_amdgcn_global_load_lds(
      (const __attribute__((address_space(1))) void*)g,
      (__attribute__((address_space(3))) void*)l, 16, 0, 0);
}

// ---------------- fp32 -> bf16 convert, all 7 tensors in one launch ----------------
__global__ void cvt_all(
    const float* __restrict__ i0, const float* __restrict__ i1, const float* __restrict__ i2,
    const float* __restrict__ i3, const float* __restrict__ i4, const float* __restrict__ i5,
    const float* __restrict__ i6,
    u16* __restrict__ o0, u16* __restrict__ o1, u16* __restrict__ o2,
    u16* __restrict__ o3, u16* __restrict__ o4, u16* __restrict__ o5,
    u16* __restrict__ o6, int nX, int nW)
{
  const int z = blockIdx.z;
  const float* in; u16* out; int n;
  switch (z){
    case 0: in=i0; out=o0; n=nX; break;
    case 1: in=i1; out=o1; n=nX; break;
    case 2: in=i2; out=o2; n=nX; break;
    case 3: in=i3; out=o3; n=nW; break;
    case 4: in=i4; out=o4; n=nW; break;
    case 5: in=i5; out=o5; n=nW; break;
    default: in=i6; out=o6; n=nW; break;
  }
  int idx = (blockIdx.x * blockDim.x + threadIdx.x) * 4;
  int stride = gridDim.x * blockDim.x * 4;
  for (int i = idx; i < n; i += stride){
    float4 v = *(const float4*)(in + i);
    u16x4 o = { f2bf(v.x), f2bf(v.y), f2bf(v.z), f2bf(v.w) };
    *(u16x4*)(out + i) = o;
  }
}

// ======== GEMM core: 128x128 tile, BK=32, 256 thr / 4 waves (2x2), 3-buf LDS ========
// Depth-2 prefetch, counted vmcnt(4), ONE barrier per K-tile, 48KB LDS -> 3 blocks/CU.
#define G4_LDSU16 24576   // 48KB total: A 3x8KB @0, B 3x8KB @24576B

__device__ __forceinline__ void stageG(const u16* __restrict__ G, int r0g, int k0,
                                       char* base, int buf, int tid){
  #pragma unroll
  for (int r=0;r<2;++r){
    int c = r*256 + tid;
    int row = c >> 2;
    int colb = ((c & 3) * 16) ^ (((row >> 2) & 3) << 4);
    load_lds16((const char*)(G + (size_t)(r0g + row)*E_DIM + k0) + colb,
               base + buf*8192 + (size_t)(r*256 + (tid >> 6)*64)*16);
  }
}

__device__ __forceinline__ void gemm4_mainloop(
    const u16* __restrict__ A, const u16* __restrict__ Bt,
    int m0, int n0, u16* smem, f32x4 (&acc)[4][4])
{
  constexpr int NT = E_DIM / 32;     // 32 K-tiles
  const int tid = threadIdx.x;
  const int lane = tid & 63;
  const int w = tid >> 6;
  const int wr = w >> 1, wc = w & 1;
  const int lr = lane & 15, lg = lane >> 4;
  char* Abase = (char*)smem;
  char* Bbase = (char*)smem + 24576;

  #pragma unroll
  for (int i=0;i<4;i++)
    #pragma unroll
    for (int j=0;j<4;j++) acc[i][j] = (f32x4){0.f,0.f,0.f,0.f};

  stageG(A,  m0, 0,  Abase, 0, tid);
  stageG(Bt, n0, 0,  Bbase, 0, tid);
  stageG(A,  m0, 32, Abase, 1, tid);
  stageG(Bt, n0, 32, Bbase, 1, tid);
  asm volatile("s_waitcnt vmcnt(4)\n" ::: "memory");   // tile 0 resident
  __builtin_amdgcn_sched_barrier(0);
  __builtin_amdgcn_s_barrier();

  const int cbx = (lg*16) ^ (((lr >> 2) & 3) << 4);

  int cur = 0;                       // t % 3
  for (int t = 0; t < NT; ++t){
    if (t + 2 < NT){
      int st3 = cur + 2; if (st3 >= 3) st3 -= 3;   // (t+2) % 3 — read at t-1, safe
      stageG(A,  m0, (t+2)*32, Abase, st3, tid);
      stageG(Bt, n0, (t+2)*32, Bbase, st3, tid);
    }
    char* Ac = Abase + cur*8192;
    char* Bc = Bbase + cur*8192;
    bf16x8 af[4], bfr[4];
    #pragma unroll
    for (int i=0;i<4;i++){
      af[i]  = *(const bf16x8*)(Ac + (wr*64 + i*16 + lr)*64 + cbx);
      bfr[i] = *(const bf16x8*)(Bc + (wc*64 + i*16 + lr)*64 + cbx);
    }
    asm volatile("s_waitcnt lgkmcnt(0)\n" ::: "memory");
    __builtin_amdgcn_sched_barrier(0);
    __builtin_amdgcn_s_setprio(1);
    #pragma unroll
    for (int i=0;i<4;i++)
      #pragma unroll
      for (int j=0;j<4;j++)
        acc[i][j] = __builtin_amdgcn_mfma_f32_16x16x32_bf16(af[i], bfr[j], acc[i][j], 0,0,0);
    __builtin_amdgcn_s_setprio(0);
    if (t + 2 < NT)      asm volatile("s_waitcnt vmcnt(4)\n" ::: "memory");
    else if (t + 1 < NT) asm volatile("s_waitcnt vmcnt(0)\n" ::: "memory");
    __builtin_amdgcn_sched_barrier(0);
    __builtin_amdgcn_s_barrier();
    cur = cur + 1; if (cur == 3) cur = 0;
  }
}

// XCD remap: 512 blocks/GEMM, XCD c owns m-panels [8c,8c+8) x all 8 n-tiles
__device__ __forceinline__ void xcd_remap_gemm(int &m0, int &n0){
  int L = blockIdx.y * 8 + blockIdx.x;     // [0,512)
  int c = L & 7, i = L >> 3;               // i in [0,64)
  int by = c*8 + (i & 7);                  // [0,64)
  int bx = i >> 3;                         // [0,8)
  m0 = by * 128; n0 = bx * 128;
}

struct QKVArgs {
  const u16* A[3]; const u16* Bw[3]; const float* bias[3];
  float scale[3]; u16* out[3];
};

// Q/K/V projections. z=0/1 write bf16 [B,H,L,D]; z=2 writes Vt [B,H,D,S] directly
// (s quad-permuted: position p holds s=perm(p), matching attn's PV fragment layout).
__global__ __launch_bounds__(256) void gemm_qkv(QKVArgs args){
  __shared__ __align__(16) u16 smem[G4_LDSU16];
  const int z = blockIdx.z;
  int m0, n0; xcd_remap_gemm(m0, n0);
  f32x4 acc[4][4];
  gemm4_mainloop(args.A[z], args.Bw[z], m0, n0, smem, acc);

  const int tid = threadIdx.x;
  const int lane = tid & 63;
  const int w = tid >> 6;
  const int wr = w >> 1, wc = w & 1;
  const int lr = lane & 15, lg = lane >> 4;
  const float* bias = args.bias[z];
  u16* outB = args.out[z];

  if (z == 2){
    // ---- fused V transpose: C-tile -> LDS -> Vt[bh][d][t0..t0+32) ----
    __syncthreads();   // main-loop LDS reads complete before overwrite
    u16* tile = smem;  // [128 n][132] u16 = 33.8KB (fits in 48KB)
    #pragma unroll
    for (int i=0;i<4;i++)
      #pragma unroll
      for (int j=0;j<4;j++){
        int n_local = wc*64 + j*16 + lr;
        u16x4 pk;
        #pragma unroll
        for (int q=0;q<4;q++) pk[q] = f2bf(acc[i][j][q] + bias[n0 + n_local]);
        *(u16x4*)&tile[n_local*132 + wr*64 + i*16 + lg*4] = pk;
      }
    __syncthreads();
    const int t0 = m0 >> 2;                 // 32 t-values per tile (m = t*4 + b)
    #pragma unroll
    for (int rr=0; rr<2; ++rr){
      int rho = (tid << 1) | rr;            // [0,512): (b, h_local, d)
      int vb = rho >> 7;
      int vh = (rho >> 6) & 1;
      int vd = rho & 63;
      int n_local = vh*64 + vd;
      int bh2 = vb*H_N + (n0 >> 6) + vh;
      u16* dst = outB + ((size_t)bh2*D_H + vd)*T_LEN + t0;
      #pragma unroll
      for (int g=0; g<4; ++g){
        u16x8 vv;
        #pragma unroll
        for (int e=0; e<8; ++e){
          int p = g*8 + e;
          int sp = (p & ~12) | ((p & 4) << 1) | ((p & 8) >> 1);   // quad-perm involution
          vv[e] = tile[n_local*132 + sp*4 + vb];
        }
        *(u16x8*)(dst + g*8) = vv;
      }
    }
  } else {
    const float scale = args.scale[z];
    #pragma unroll
    for (int i=0;i<4;i++)
      #pragma unroll
      for (int j=0;j<4;j++)
        #pragma unroll
        for (int q=0;q<4;q++){
          int m = m0 + wr*64 + i*16 + lg*4 + q;
          int n = n0 + wc*64 + j*16 + lr;
          float v = (acc[i][j][q] + bias[n]) * scale;
          int t = m >> 2, b = m & 3;             // rows of [L,B,E]: m = t*B + b
          int h = n >> 6, d = n & 63;
          outB[ ((size_t)(b*H_N + h)*T_LEN + t)*D_H + d ] = f2bf(v);
        }
  }
}

// Output projection: AO [B,T,E] -> d_out [T,B,E] fp32
__global__ __launch_bounds__(256) void gemm_out(
    const u16* __restrict__ A, const u16* __restrict__ Bt,
    const float* __restrict__ bias, float* __restrict__ outF)
{
  __shared__ __align__(16) u16 smem[G4_LDSU16];
  int m0, n0; xcd_remap_gemm(m0, n0);
  f32x4 acc[4][4];
  gemm4_mainloop(A, Bt, m0, n0, smem, acc);

  const int lane = threadIdx.x & 63;
  const int w = threadIdx.x >> 6;
  const int wr = w >> 1, wc = w & 1;
  const int lr = lane & 15, lg = lane >> 4;
  #pragma unroll
  for (int i=0;i<4;i++)
    #pragma unroll
    for (int j=0;j<4;j++)
      #pragma unroll
      for (int q=0;q<4;q++){
        int m = m0 + wr*64 + i*16 + lg*4 + q;
        int n = n0 + wc*64 + j*16 + lr;
        float v = acc[i][j][q] + bias[n];
        int b = m >> 11, t = m & 2047;         // rows of AO [B,T,E]: m = b*T + t
        outF[ (size_t)(t*B_SZ + b)*E_DIM + n ] = v;
      }
}

// ---------------- causal flash attention, 32x32 MFMA, QBLK=128, KVBLK=64 ----------------
// R15 structure (proven 74.4us): 2-phase, 2-buffer, tree max/rsum, in-register P.
__global__ __launch_bounds__(256) void attn_fwd(
    const u16* __restrict__ Qb, const u16* __restrict__ Kb,
    const u16* __restrict__ Vt, u16* __restrict__ AO)
{
  __shared__ __align__(16) u16 smem[4*64*64];
  u16* Ks = smem;
  u16* Vs = smem + 2*64*64;
  const int tid = threadIdx.x;
  const int lane = tid & 63;
  const int wq = tid >> 6;
  const int l31 = lane & 31;
  const int hi = lane >> 5;
  int bh, px;
  {
    int L = blockIdx.y * 8 + blockIdx.x;
    int c = L & 7, i2 = L >> 3;
    bh = c*8 + (i2 & 7);
    px = i2 >> 3;
  }
  const u16* Kbase = Kb + (size_t)bh * T_LEN * D_H;
  const u16* Vbase = Vt + (size_t)bh * D_H * T_LEN;
  const int b_ = bh >> 4, h = bh & 15;

  auto STAGE = [&](int j, int b){
    int s0 = j * 64;
    #pragma unroll
    for (int r=0;r<2;++r){
      int c = r*256 + tid;
      int row = c >> 3;
      int colb = (c & 7) * 16;
      int scolb = colb ^ ((row & 7) << 4);
      load_lds16((const char*)(Kbase + (size_t)(s0 + row)*D_H) + scolb,
                 (char*)Ks + b*8192 + (r*256 + wq*64)*16);
      load_lds16((const char*)(Vbase + (size_t)row*T_LEN + s0) + scolb,
                 (char*)Vs + b*8192 + (r*256 + wq*64)*16);
    }
  };

  #pragma unroll 1
  for (int ph = 0; ph < 2; ++ph){
    const int qt = ph ? px : (NQT - 1 - px);
    const int qb = qt * 128;
    const int qg = qb + wq*32 + l31;

    bf16x8 qf[4];
    {
      const u16* qp = Qb + (size_t)bh*T_LEN*D_H + (size_t)qg*D_H + hi*8;
      #pragma unroll
      for (int kk=0;kk<4;++kk) qf[kk] = *(const bf16x8*)(qp + kk*16);
    }

    f32x16 o[2];
    #pragma unroll
    for (int f=0;f<2;++f)
      #pragma unroll
      for (int r=0;r<16;++r) o[f][r] = 0.f;
    float m_run = -INFINITY, l_run = 0.f;

    const int ntiles = 2*qt + 2;
    __syncthreads();
    STAGE(0, 0);
    __syncthreads();

    for (int j = 0; j < ntiles; ++j){
      const int cur = j & 1;
      if (j + 1 < ntiles) STAGE(j+1, cur^1);
      const char* Kc = (const char*)Ks + cur*8192;
      const char* Vc = (const char*)Vs + cur*8192;

      const bool fullmask = (j == 2*qt + 1) && (wq < 2);
      if (!fullmask){
        f32x16 st[2];
        #pragma unroll
        for (int i=0;i<2;++i)
          #pragma unroll
          for (int r=0;r<16;++r) st[i][r] = 0.f;
        __builtin_amdgcn_s_setprio(1);
        #pragma unroll
        for (int i=0;i<2;++i){
          #pragma unroll
          for (int kk=0;kk<4;++kk){
            int row = i*32 + l31;
            int colb = (kk*32 + hi*16) ^ ((row & 7) << 4);
            bf16x8 kf = *(const bf16x8*)(Kc + row*128 + colb);
            st[i] = __builtin_amdgcn_mfma_f32_32x32x16_bf16(kf, qf[kk], st[i], 0,0,0);
          }
        }
        __builtin_amdgcn_s_setprio(0);

        const int s0 = j*64;
        float mx = -INFINITY;
        if (j >= 2*qt){
          #pragma unroll
          for (int i=0;i<2;++i)
            #pragma unroll
            for (int r=0;r<16;++r){
              int sg = s0 + i*32 + (r&3) + 8*(r>>2) + 4*hi;
              float v = (sg > qg) ? -INFINITY : st[i][r];
              st[i][r] = v;
              mx = fmaxf(mx, v);
            }
        } else {
          mx = fmaxf(vmax16(st[0]), vmax16(st[1]));
        }
        mx = xhalf_max(mx);

        // defer-max: rescale only when needed (P bounded by 2^8)
        if (!__all(mx <= m_run + 8.0f)){
          float m_new = fmaxf(m_run, mx);
          float sc = fexp2(m_run - m_new);
          l_run *= sc;
          #pragma unroll
          for (int f=0;f<2;++f)
            #pragma unroll
            for (int r=0;r<16;++r) o[f][r] *= sc;
          m_run = m_new;
        }

        // exp + tree row-sum (4 independent chains)
        float rs0 = 0.f, rs1 = 0.f, rs2 = 0.f, rs3 = 0.f;
        #pragma unroll
        for (int i=0;i<2;++i)
          #pragma unroll
          for (int r=0;r<16;++r){
            float p = fexp2(st[i][r] - m_run);
            st[i][r] = p;
            if ((r & 3) == 0) rs0 += p;
            else if ((r & 3) == 1) rs1 += p;
            else if ((r & 3) == 2) rs2 += p;
            else rs3 += p;
          }
        float rsum = (rs0 + rs1) + (rs2 + rs3);
        rsum = xhalf_sum(rsum);
        l_run += rsum;

        // pack P into PV B-fragments (V s-order quad-permuted to match)
        u32x4 Bfr[4];
        #pragma unroll
        for (int i=0;i<2;++i){
          Bfr[2*i]   = (u32x4){ cvtpk(st[i][0],  st[i][1]),  cvtpk(st[i][2],  st[i][3]),
                                cvtpk(st[i][4],  st[i][5]),  cvtpk(st[i][6],  st[i][7]) };
          Bfr[2*i+1] = (u32x4){ cvtpk(st[i][8],  st[i][9]),  cvtpk(st[i][10], st[i][11]),
                                cvtpk(st[i][12], st[i][13]), cvtpk(st[i][14], st[i][15]) };
        }

        // O^T += V^T · P^T
        __builtin_amdgcn_s_setprio(1);
        #pragma unroll
        for (int ss=0; ss<4; ++ss){
          bf16x8 pb = __builtin_bit_cast(bf16x8, Bfr[ss]);
          #pragma unroll
          for (int f=0; f<2; ++f){
            int row = f*32 + l31;
            int colb = (ss*32 + hi*16) ^ ((row & 7) << 4);
            bf16x8 vf = *(const bf16x8*)(Vc + row*128 + colb);
            o[f] = __builtin_amdgcn_mfma_f32_32x32x16_bf16(vf, pb, o[f], 0,0,0);
          }
        }
        __builtin_amdgcn_s_setprio(0);
      }
      __syncthreads();
    }

    float linv = 1.f / l_run;
    {
      char* Osh = (char*)smem;
      unsigned base = wq*4352;
      #pragma unroll
      for (int f=0;f<2;++f)
        #pragma unroll
        for (int m=0;m<8;++m){
          unsigned word = cvtpk(o[f][2*m]*linv, o[f][2*m+1]*linv);
          int d0 = (m&1)*2 + 8*(m>>1) + 4*hi + 32*f;
          *(unsigned*)(Osh + base + l31*136 + d0*2) = word;
        }
    }
    __syncthreads();
    {
      int q = tid >> 1, half = tid & 1;
      const char* src = (const char*)smem + (q>>5)*4352 + (q&31)*136 + half*64;
      u16* dst = AO + ((size_t)(b_*T_LEN + qb + q))*E_DIM + h*D_H + half*32;
      #pragma unroll
      for (int k=0;k<4;++k)
        *(u16x8*)(dst + k*8) = *(const u16x8*)(src + k*16);
    }
  }
}

extern "C" void kernel_launch(void* const* d_in, const int* in_sizes, int n_in,
                              void* d_out, int out_size, void* d_ws, size_t ws_size,
                              hipStream_t stream){
  const float* query = (const float*)d_in[0];
  const float* key   = (const float*)d_in[1];
  const float* value = (const float*)d_in[2];
  const float* Wq = (const float*)d_in[4];
  const float* bq = (const float*)d_in[5];
  const float* Wk = (const float*)d_in[6];
  const float* bk = (const float*)d_in[7];
  const float* Wv = (const float*)d_in[8];
  const float* bv = (const float*)d_in[9];
  const float* Wo = (const float*)d_in[10];
  const float* bo = (const float*)d_in[11];

  char* ws = (char*)d_ws;
  const size_t SZ_X = (size_t)M_ROWS * E_DIM * 2;   // 16 MB
  const size_t SZ_W = (size_t)E_DIM * E_DIM * 2;    // 2 MB
  u16* Xq  = (u16*)(ws);                    // reused as AO after Q-proj
  u16* Xk  = (u16*)(ws + SZ_X);
  u16* Xv  = (u16*)(ws + 2*SZ_X);
  u16* Wqb = (u16*)(ws + 3*SZ_X);
  u16* Wkb = (u16*)(ws + 3*SZ_X + 1*SZ_W);
  u16* Wvb = (u16*)(ws + 3*SZ_X + 2*SZ_W);
  u16* Wob = (u16*)(ws + 3*SZ_X + 3*SZ_W);
  u16* Qb  = (u16*)(ws + 3*SZ_X + 4*SZ_W);
  u16* Kb  = (u16*)(ws + 4*SZ_X + 4*SZ_W);
  u16* Vt  = (u16*)(ws + 5*SZ_X + 4*SZ_W);  // V written transposed directly by gemm_qkv z=2
  u16* AO  = Xq;

  const int nX = M_ROWS * E_DIM;
  const int nW = E_DIM * E_DIM;
  cvt_all<<<dim3(1024,1,7), 256, 0, stream>>>(
      query, key, value, Wq, Wk, Wv, Wo,
      Xq, Xk, Xv, Wqb, Wkb, Wvb, Wob, nX, nW);

  const float QSCALE = 0.125f * 1.44269504f;   // 1/sqrt(D) * log2(e)
  QKVArgs qa;
  qa.A[0]=Xq;  qa.A[1]=Xk;  qa.A[2]=Xv;
  qa.Bw[0]=Wqb; qa.Bw[1]=Wkb; qa.Bw[2]=Wvb;
  qa.bias[0]=bq; qa.bias[1]=bk; qa.bias[2]=bv;
  qa.scale[0]=QSCALE; qa.scale[1]=1.0f; qa.scale[2]=1.0f;
  qa.out[0]=Qb; qa.out[1]=Kb; qa.out[2]=Vt;
  gemm_qkv<<<dim3(8, M_ROWS/128, 3), 256, 0, stream>>>(qa);
  attn_fwd<<<dim3(8, B_SZ*H_N), 256, 0, stream>>>(Qb, Kb, Vt, AO);
  gemm_out<<<dim3(8, M_ROWS/128), 256, 0, stream>>>(AO, Wob, bo, (float*)d_out);
}